// Round 8
// baseline (198.509 us; speedup 1.0000x reference)
//
#include <hip/hip_runtime.h>

#define B_    32
#define H_    640
#define W_    368
#define OH    634          // H - 6
#define OW    362          // W - 6
#define CHUNK 8            // output rows per block; 80 chunks -> 2560 blocks = 10/CU
#define NCHUNK 80          // 79 full chunks + last (2 rows); 79*8+2 = 634
#define NBLK  (NCHUNK * B_)          // 2560
#define GROUPS 64

// d_ws layout (floats):
//   [0..31]      per-batch max of target (int-bits atomicMax; 0xAA poison is negative,
//                any positive-float bits win, so no pre-zeroing needed)
//   [64..1087]   64 partial-sum slots, stride 16 floats (64 B); zeroed by k_max blk 0
//
// Session lessons baked in:
//  R1/R2: no per-block device-scope __threadfence (~70 ns serialized each; +110 us).
//  R4:    no per-row __syncthreads (implicit vmcnt(0) drains stage queue; +3 us).
//  R3/R5/R7: register-prefetch == LDS+counted-vmcnt == LDS+barriers-3us -> the
//         memory path is NOT binding. Only VALU-count cuts moved the needle (R6).
//  R6:    packed fp32 (v_pk_*) -33% VALU -> -7.3 us. VALUBusy ~57%: ~43% of
//         cycles all 6 waves/SIMD stalled together. This round buys TLP instead:
//         VGPR<=64 (drop prefetch, force via __launch_bounds__(192,8)) + CHUNK=8
//         (2560 blocks = 10 blk/CU) -> 30 waves/CU (+25% issue capacity, +9% halo).
//         Spill tell: k_ssim WRITE_SIZE >> 1 MB -> revert to R6.
#define SLOT0 64
#define STRIDE 16

typedef float f2 __attribute__((ext_vector_type(2)));

__global__ __launch_bounds__(256) void k_max(const float* __restrict__ tgt,
                                             float* __restrict__ ws) {
    if (blockIdx.x == 0) {                     // zero slots (stream order vs k_ssim)
        for (int i = threadIdx.x; i < GROUPS * STRIDE; i += 256)
            ws[SLOT0 + i] = 0.0f;
    }
    const int b   = blockIdx.x >> 5;
    const int seg = blockIdx.x & 31;
    const int perseg = (H_ * W_) / 32;         // 7360 floats
    const float4* p = (const float4*)(tgt + (size_t)b * (H_ * W_) + (size_t)seg * perseg);
    const int n4 = perseg / 4;                 // 1840
    float m = 0.0f;
    for (int i = threadIdx.x; i < n4; i += 256) {
        float4 v = p[i];
        m = fmaxf(m, fmaxf(fmaxf(v.x, v.y), fmaxf(v.z, v.w)));
    }
    #pragma unroll
    for (int off = 32; off; off >>= 1)
        m = fmaxf(m, __shfl_down(m, off, 64));
    __shared__ float sm[4];
    const int lane = threadIdx.x & 63, wv = threadIdx.x >> 6;
    if (lane == 0) sm[wv] = m;
    __syncthreads();
    if (threadIdx.x == 0) {
        m = fmaxf(fmaxf(sm[0], sm[1]), fmaxf(sm[2], sm[3]));
        atomicMax((int*)ws + b, __float_as_int(m));   // inputs >= 0
    }
}

__device__ __forceinline__ void loadrow(const float* __restrict__ xr,
                                        const float* __restrict__ yr,
                                        f2 xn[4], f2 yn[4]) {
    const f2* xp = (const f2*)xr;   // (r*368 + 2t)*4 is always 8B-aligned
    const f2* yp = (const f2*)yr;
    xn[0] = xp[0]; xn[1] = xp[1]; xn[2] = xp[2]; xn[3] = xp[3];
    yn[0] = yp[0]; yn[1] = yp[1]; yn[2] = yp[2]; yn[3] = yp[3];
}

#define FMA2(a, b, c) __builtin_elementwise_fma((a), (b), (c))

// Horizontal 7-sums for TWO adjacent windows, PACKED-FP32 (R6, verified absmax 0).
// h[q] = f2{even,odd}; q: 0=x, 1=y, 2=s(xx+yy), 3=xy.
__device__ __forceinline__ void hsum2v(const f2 xn[4], const f2 yn[4], f2 h[4]) {
    const f2 px = xn[0] + xn[1] + xn[2];                    // 2 pk_add
    const f2 py = yn[0] + yn[1] + yn[2];                    // 2 pk_add
    f2 ps = xn[0] * xn[0];                                  // 1 pk_mul
    ps = FMA2(xn[1], xn[1], ps);
    ps = FMA2(xn[2], xn[2], ps);
    ps = FMA2(yn[0], yn[0], ps);
    ps = FMA2(yn[1], yn[1], ps);
    ps = FMA2(yn[2], yn[2], ps);                            // 5 pk_fma
    f2 pp = xn[0] * yn[0];
    pp = FMA2(xn[1], yn[1], pp);
    pp = FMA2(xn[2], yn[2], pp);                            // 1 mul + 2 fma

    const float x6 = xn[3].x, x7 = xn[3].y;
    const float y6 = yn[3].x, y7 = yn[3].y;
    const float x0 = xn[0].x, y0 = yn[0].x;

    const float hx = px.x + px.y + x6;
    const float hy = py.x + py.y + y6;
    const float hs = fmaf(x6, x6, fmaf(y6, y6, ps.x + ps.y));
    const float hxy = fmaf(x6, y6, pp.x + pp.y);

    h[0] = (f2){hx,  hx - x0 + x7};
    h[1] = (f2){hy,  hy - y0 + y7};
    h[2] = (f2){hs,  fmaf(x7, x7, fmaf(y7, y7,
                     fmaf(-x0, x0, fmaf(-y0, y0, hs))))};
    h[3] = (f2){hxy, fmaf(x7, y7, fmaf(-x0, y0, hxy))};
}

// __launch_bounds__(192, 8): 8 waves/EU -> VGPR capped at 64. The 4-quantity
// packed ring + JIT loads (NO next-row prefetch) is ~60 regs of live state —
// sized to fit. (The old spill was the 5-quantity/70-reg ring forced to 64.)
// JIT-load latency is covered by TLP: 30 waves/CU, ~7.5 waves/SIMD.
__global__ __launch_bounds__(192, 8) void k_ssim(const float* __restrict__ X,
                                                 const float* __restrict__ Y,
                                                 float* __restrict__ ws) {
    const int t    = threadIdx.x;              // 0..191
    const int w    = t >> 6;
    const int lane = t & 63;
    const int b    = blockIdx.y;
    const int r0   = blockIdx.x * CHUNK;
    const int outRows = min(CHUNK, OH - r0);   // 8, or 2 for last chunk
    const int c    = 2 * t;                    // base output col
    const bool colOK = (c < OW);               // t <= 180

    const float dr  = ws[b];
    float C1 = 0.01f * dr; C1 *= C1;
    float C2 = 0.03f * dr; C2 *= C2;
    const f2 c1s   = (f2){C1 * 2401.0f, C1 * 2401.0f};   // scaled-domain constants
    const f2 c2s   = (f2){C2 * 2401.0f, C2 * 2401.0f};
    const f2 covn2 = (f2){2.0f * (49.0f / 48.0f), 2.0f * (49.0f / 48.0f)};
    const f2 covn  = (f2){49.0f / 48.0f, 49.0f / 48.0f};
    const f2 k49   = (f2){49.0f, 49.0f};
    const f2 two   = (f2){2.0f, 2.0f};

    const float* xb = X + (size_t)b * (H_ * W_) + c;
    const float* yb = Y + (size_t)b * (H_ * W_) + c;

    f2 accv = (f2){0.0f, 0.0f};

    if (colOK) {
        f2 ring[4][7];                         // [quantity][row slot] — compile-time idx
        f2 tot[4] = {};
        f2 h[4];
        f2 xn[4], yn[4];

        #pragma unroll
        for (int p = 0; p < 6; ++p) {          // prime 6 halo rows (JIT load)
            loadrow(xb + (size_t)(r0 + p) * W_, yb + (size_t)(r0 + p) * W_, xn, yn);
            hsum2v(xn, yn, h);
            #pragma unroll
            for (int q = 0; q < 4; ++q) {
                ring[q][p] = h[q];
                tot[q] += h[q];
            }
        }

        for (int ii = 0; ii < outRows; ii += 7) {
            #pragma unroll
            for (int p = 0; p < 7; ++p) {      // ring slot == p (compile-time)
                const int i = ii + p;
                if (i >= outRows) break;       // block-uniform
                loadrow(xb + (size_t)(r0 + i + 6) * W_,   // JIT load row i+6
                        yb + (size_t)(r0 + i + 6) * W_, xn, yn);
                hsum2v(xn, yn, h);

                #pragma unroll
                for (int q = 0; q < 4; ++q)
                    tot[q] += h[q];            // v_pk_add

                {   // SSIM for both columns, fully packed (2 scalar rcp only)
                    const f2 tx = tot[0], ty = tot[1], ts = tot[2], txy = tot[3];
                    const f2 pxy = tx * ty;
                    const f2 A1  = FMA2(pxy, two, c1s);
                    const f2 s2  = FMA2(tx, tx, ty * ty);
                    const f2 B1  = s2 + c1s;
                    const f2 mxy = FMA2(k49, txy, -pxy);
                    const f2 A2  = FMA2(covn2, mxy, c2s);
                    const f2 vs  = FMA2(k49, ts, -s2);
                    const f2 B2  = FMA2(covn, vs, c2s);
                    const f2 den = B1 * B2;
                    f2 rv;
                    rv.x = __builtin_amdgcn_rcpf(den.x);
                    rv.y = __builtin_amdgcn_rcpf(den.y);
                    accv = FMA2(A1 * A2, rv, accv);
                }

                const int sn = (p + 6) % 7;    // retire slot p, insert new in slot sn
                #pragma unroll
                for (int q = 0; q < 4; ++q) {
                    tot[q] -= ring[q][p];      // v_pk_sub
                    ring[q][sn] = h[q];
                }
            }
        }
    }

    // wave reduce, LDS across 3 waves, ONE scattered atomic per block. No fences!
    float acc = accv.x + accv.y;
    #pragma unroll
    for (int off = 32; off; off >>= 1)
        acc += __shfl_down(acc, off, 64);
    __shared__ float sm[3];
    if (lane == 0) sm[w] = acc;
    __syncthreads();
    if (t == 0) {
        const float s = sm[0] + sm[1] + sm[2];
        const int blk = blockIdx.y * NCHUNK + blockIdx.x;
        atomicAdd(ws + SLOT0 + (blk & (GROUPS - 1)) * STRIDE, s);  // 64 independent lines
    }
}

__global__ __launch_bounds__(64) void k_fin(const float* __restrict__ ws,
                                            float* __restrict__ out) {
    float v = ws[SLOT0 + threadIdx.x * STRIDE];   // kernel boundary orders prior atomics
    #pragma unroll
    for (int off = 32; off; off >>= 1)
        v += __shfl_down(v, off, 64);
    if (threadIdx.x == 0)
        out[0] = 1.0f - v * (1.0f / (32.0f * 634.0f * 362.0f));
}

extern "C" void kernel_launch(void* const* d_in, const int* in_sizes, int n_in,
                              void* d_out, int out_size, void* d_ws, size_t ws_size,
                              hipStream_t stream) {
    const float* X = (const float*)d_in[0];   // 'output'
    const float* Y = (const float*)d_in[1];   // 'target'
    float* ws = (float*)d_ws;

    k_max<<<dim3(1024), dim3(256), 0, stream>>>(Y, ws);
    k_ssim<<<dim3(NCHUNK, B_), dim3(192), 0, stream>>>(X, Y, ws);
    k_fin<<<dim3(1), dim3(64), 0, stream>>>(ws, (float*)d_out);
}

// Round 9
// 110.611 us; speedup vs baseline: 1.7947x; 1.7947x over previous
//
#include <hip/hip_runtime.h>

#define B_    32
#define H_    640
#define W_    368
#define OH    634          // H - 6
#define OW    362          // W - 6
#define CHUNK 10           // output rows per block; 2048 blocks = 8/CU, 6 waves/SIMD
#define NCHUNK 64          // 63 full chunks + last (4 rows); 63*10+4 = 634
#define NBLK  (NCHUNK * B_)          // 2048
#define GROUPS 64

// d_ws layout (floats):
//   [0..31]      per-batch max of target (int-bits atomicMax; 0xAA poison is negative,
//                any positive-float bits win, so no pre-zeroing needed)
//   [64..1087]   64 partial-sum slots, stride 16 floats (64 B); zeroed by k_max blk 0
//
// Session lessons baked in:
//  R1/R2: no per-block device-scope __threadfence (~70 ns serialized each; +110 us).
//  R4:    no per-row __syncthreads (implicit vmcnt(0) drains stage queue; +3 us).
//  R3/R5/R7: register-prefetch == LDS+counted-vmcnt == LDS+barriers-3us -> the
//         memory path is NOT binding; do not re-litigate staging.
//  R6:    packed fp32 (v_pk_*) -33% VALU -> -7.3 us. The ONLY lever that moved.
//  R8:    __launch_bounds__(192,8) capped VGPR at 32 (cap ~ 256/arg, not 512/arg):
//         ring spilled (WRITE_SIZE 66 KB -> 178 MB), k_ssim 21 -> 120 us. The
//         ~76-VGPR ring is this algorithm's irreducible state; 6 waves/SIMD is
//         the occupancy ceiling. DO NOT clamp launch bounds.
#define SLOT0 64
#define STRIDE 16

typedef float f2 __attribute__((ext_vector_type(2)));

__global__ __launch_bounds__(256) void k_max(const float* __restrict__ tgt,
                                             float* __restrict__ ws) {
    if (blockIdx.x == 0) {                     // zero slots (stream order vs k_ssim)
        for (int i = threadIdx.x; i < GROUPS * STRIDE; i += 256)
            ws[SLOT0 + i] = 0.0f;
    }
    const int b   = blockIdx.x >> 5;
    const int seg = blockIdx.x & 31;
    const int perseg = (H_ * W_) / 32;         // 7360 floats
    const float4* p = (const float4*)(tgt + (size_t)b * (H_ * W_) + (size_t)seg * perseg);
    const int n4 = perseg / 4;                 // 1840
    float m = 0.0f;
    for (int i = threadIdx.x; i < n4; i += 256) {
        float4 v = p[i];
        m = fmaxf(m, fmaxf(fmaxf(v.x, v.y), fmaxf(v.z, v.w)));
    }
    #pragma unroll
    for (int off = 32; off; off >>= 1)
        m = fmaxf(m, __shfl_down(m, off, 64));
    __shared__ float sm[4];
    const int lane = threadIdx.x & 63, wv = threadIdx.x >> 6;
    if (lane == 0) sm[wv] = m;
    __syncthreads();
    if (threadIdx.x == 0) {
        m = fmaxf(fmaxf(sm[0], sm[1]), fmaxf(sm[2], sm[3]));
        atomicMax((int*)ws + b, __float_as_int(m));   // inputs >= 0
    }
}

__device__ __forceinline__ void loadrow(const float* __restrict__ xr,
                                        const float* __restrict__ yr,
                                        f2 xn[4], f2 yn[4]) {
    const f2* xp = (const f2*)xr;   // (r*368 + 2t)*4 is always 8B-aligned
    const f2* yp = (const f2*)yr;
    xn[0] = xp[0]; xn[1] = xp[1]; xn[2] = xp[2]; xn[3] = xp[3];
    yn[0] = yp[0]; yn[1] = yp[1]; yn[2] = yp[2]; yn[3] = yp[3];
}

#define FMA2(a, b, c) __builtin_elementwise_fma((a), (b), (c))

// Horizontal 7-sums for TWO adjacent windows, PACKED-FP32 (R6, verified absmax 0).
// h[q] = f2{even,odd}; q: 0=x, 1=y, 2=s(xx+yy), 3=xy.
__device__ __forceinline__ void hsum2v(const f2 xn[4], const f2 yn[4], f2 h[4]) {
    const f2 px = xn[0] + xn[1] + xn[2];                    // 2 pk_add
    const f2 py = yn[0] + yn[1] + yn[2];                    // 2 pk_add
    f2 ps = xn[0] * xn[0];                                  // 1 pk_mul
    ps = FMA2(xn[1], xn[1], ps);
    ps = FMA2(xn[2], xn[2], ps);
    ps = FMA2(yn[0], yn[0], ps);
    ps = FMA2(yn[1], yn[1], ps);
    ps = FMA2(yn[2], yn[2], ps);                            // 5 pk_fma
    f2 pp = xn[0] * yn[0];
    pp = FMA2(xn[1], yn[1], pp);
    pp = FMA2(xn[2], yn[2], pp);                            // 1 mul + 2 fma

    const float x6 = xn[3].x, x7 = xn[3].y;
    const float y6 = yn[3].x, y7 = yn[3].y;
    const float x0 = xn[0].x, y0 = yn[0].x;

    const float hx = px.x + px.y + x6;
    const float hy = py.x + py.y + y6;
    const float hs = fmaf(x6, x6, fmaf(y6, y6, ps.x + ps.y));
    const float hxy = fmaf(x6, y6, pp.x + pp.y);

    h[0] = (f2){hx,  hx - x0 + x7};
    h[1] = (f2){hy,  hy - y0 + y7};
    h[2] = (f2){hs,  fmaf(x7, x7, fmaf(y7, y7,
                     fmaf(-x0, x0, fmaf(-y0, y0, hs))))};
    h[3] = (f2){hxy, fmaf(x7, y7, fmaf(-x0, y0, hxy))};
}

// Base: R3 structure (register prefetch, no barriers/asm in the loop) + R6 packing.
// NOTE: no min-waves clamp! (R8: clamping spilled the ring.) Unconstrained alloc
// ~76 VGPR -> 6 waves/SIMD, 8 blocks/CU, 2048 blocks exactly fill the machine.
__global__ __launch_bounds__(192) void k_ssim(const float* __restrict__ X,
                                              const float* __restrict__ Y,
                                              float* __restrict__ ws) {
    const int t    = threadIdx.x;              // 0..191
    const int w    = t >> 6;
    const int lane = t & 63;
    const int b    = blockIdx.y;
    const int r0   = blockIdx.x * CHUNK;
    const int outRows = min(CHUNK, OH - r0);   // 10, or 4 for last chunk
    const int c    = 2 * t;                    // base output col
    const bool colOK = (c < OW);               // t <= 180

    const float dr  = ws[b];
    float C1 = 0.01f * dr; C1 *= C1;
    float C2 = 0.03f * dr; C2 *= C2;
    const f2 c1s   = (f2){C1 * 2401.0f, C1 * 2401.0f};   // scaled-domain constants
    const f2 c2s   = (f2){C2 * 2401.0f, C2 * 2401.0f};
    const f2 covn2 = (f2){2.0f * (49.0f / 48.0f), 2.0f * (49.0f / 48.0f)};
    const f2 covn  = (f2){49.0f / 48.0f, 49.0f / 48.0f};
    const f2 k49   = (f2){49.0f, 49.0f};
    const f2 two   = (f2){2.0f, 2.0f};

    const float* xb = X + (size_t)b * (H_ * W_) + c;
    const float* yb = Y + (size_t)b * (H_ * W_) + c;

    f2 accv = (f2){0.0f, 0.0f};

    if (colOK) {
        f2 ring[4][7];                         // [quantity][row slot] — compile-time idx
        f2 tot[4] = {};
        f2 h[4];
        f2 xn[4], yn[4];

        #pragma unroll
        for (int p = 0; p < 6; ++p) {          // prime 6 halo rows
            loadrow(xb + (size_t)(r0 + p) * W_, yb + (size_t)(r0 + p) * W_, xn, yn);
            hsum2v(xn, yn, h);
            #pragma unroll
            for (int q = 0; q < 4; ++q) {
                ring[q][p] = h[q];
                tot[q] += h[q];                // v_pk_add
            }
        }
        loadrow(xb + (size_t)(r0 + 6) * W_, yb + (size_t)(r0 + 6) * W_, xn, yn);

        for (int ii = 0; ii < outRows; ii += 7) {
            #pragma unroll
            for (int p = 0; p < 7; ++p) {      // ring slot == p (compile-time)
                const int i = ii + p;
                if (i >= outRows) break;       // block-uniform
                hsum2v(xn, yn, h);             // consume prefetched row r0+i+6
                if (i + 1 < outRows)           // prefetch row r0+i+7 (covered by VALU below)
                    loadrow(xb + (size_t)(r0 + i + 7) * W_, yb + (size_t)(r0 + i + 7) * W_, xn, yn);

                #pragma unroll
                for (int q = 0; q < 4; ++q)
                    tot[q] += h[q];            // 4x v_pk_add

                {   // SSIM for both columns, fully packed (2 scalar rcp only)
                    const f2 tx = tot[0], ty = tot[1], ts = tot[2], txy = tot[3];
                    const f2 pxy = tx * ty;
                    const f2 A1  = FMA2(pxy, two, c1s);
                    const f2 s2  = FMA2(tx, tx, ty * ty);
                    const f2 B1  = s2 + c1s;
                    const f2 mxy = FMA2(k49, txy, -pxy);
                    const f2 A2  = FMA2(covn2, mxy, c2s);
                    const f2 vs  = FMA2(k49, ts, -s2);
                    const f2 B2  = FMA2(covn, vs, c2s);
                    const f2 den = B1 * B2;
                    f2 rv;
                    rv.x = __builtin_amdgcn_rcpf(den.x);
                    rv.y = __builtin_amdgcn_rcpf(den.y);
                    accv = FMA2(A1 * A2, rv, accv);
                }

                const int sn = (p + 6) % 7;    // retire slot p, insert new in slot sn
                #pragma unroll
                for (int q = 0; q < 4; ++q) {
                    tot[q] -= ring[q][p];      // v_pk_sub
                    ring[q][sn] = h[q];
                }
            }
        }
    }

    // wave reduce, LDS across 3 waves, ONE scattered atomic per block. No fences!
    float acc = accv.x + accv.y;
    #pragma unroll
    for (int off = 32; off; off >>= 1)
        acc += __shfl_down(acc, off, 64);
    __shared__ float sm[3];
    if (lane == 0) sm[w] = acc;
    __syncthreads();
    if (t == 0) {
        const float s = sm[0] + sm[1] + sm[2];
        const int blk = blockIdx.y * NCHUNK + blockIdx.x;
        atomicAdd(ws + SLOT0 + (blk & (GROUPS - 1)) * STRIDE, s);  // 64 independent lines
    }
}

__global__ __launch_bounds__(64) void k_fin(const float* __restrict__ ws,
                                            float* __restrict__ out) {
    float v = ws[SLOT0 + threadIdx.x * STRIDE];   // kernel boundary orders prior atomics
    #pragma unroll
    for (int off = 32; off; off >>= 1)
        v += __shfl_down(v, off, 64);
    if (threadIdx.x == 0)
        out[0] = 1.0f - v * (1.0f / (32.0f * 634.0f * 362.0f));
}

extern "C" void kernel_launch(void* const* d_in, const int* in_sizes, int n_in,
                              void* d_out, int out_size, void* d_ws, size_t ws_size,
                              hipStream_t stream) {
    const float* X = (const float*)d_in[0];   // 'output'
    const float* Y = (const float*)d_in[1];   // 'target'
    float* ws = (float*)d_ws;

    k_max<<<dim3(1024), dim3(256), 0, stream>>>(Y, ws);
    k_ssim<<<dim3(NCHUNK, B_), dim3(192), 0, stream>>>(X, Y, ws);
    k_fin<<<dim3(1), dim3(64), 0, stream>>>(ws, (float*)d_out);
}